// Round 1
// baseline (277.320 us; speedup 1.0000x reference)
//
#include <hip/hip_runtime.h>

#define NROW 128
#define NZ   8128      // 128*127/2
#define EPSF 1e-12f

// One thread per (batch, row). Row i of batch b:
//   L[i,j] = z[i,j] * sqrt(max(1 - s, EPS)) for j < i   (s accumulates L^2)
//   L[i,i] = sqrt(max(1 - s, EPS)),  L[i,j>i] = 0
// z for row i is contiguous at offset b*NZ + i*(i-1)/2 (tril row-major).
__global__ __launch_bounds__(256) void chol_from_z_kernel(
    const float* __restrict__ z, float* __restrict__ out, int nrows_total)
{
    int gid = blockIdx.x * blockDim.x + threadIdx.x;
    if (gid >= nrows_total) return;

    const int b = gid >> 7;          // gid / 128
    const int i = gid & 127;         // row within batch

    const float* __restrict__ zr = z + (size_t)b * NZ + (size_t)((i * (i - 1)) >> 1);
    float* __restrict__ orow = out + (size_t)gid * NROW;

    float s = 0.0f;
    for (int jb = 0; jb < NROW; jb += 4) {
        float v0 = 0.0f, v1 = 0.0f, v2 = 0.0f, v3 = 0.0f;
        #pragma unroll
        for (int t = 0; t < 4; ++t) {
            const int j = jb + t;
            float val = 0.0f;
            if (j < i) {
                const float sq = __builtin_amdgcn_sqrtf(fmaxf(1.0f - s, EPSF));
                val = zr[j] * sq;
                s = fmaf(val, val, s);
            } else if (j == i) {
                val = __builtin_amdgcn_sqrtf(fmaxf(1.0f - s, EPSF));
            }
            if (t == 0) v0 = val;
            else if (t == 1) v1 = val;
            else if (t == 2) v2 = val;
            else v3 = val;
        }
        float4 v = make_float4(v0, v1, v2, v3);
        *reinterpret_cast<float4*>(orow + jb) = v;
    }
}

extern "C" void kernel_launch(void* const* d_in, const int* in_sizes, int n_in,
                              void* d_out, int out_size, void* d_ws, size_t ws_size,
                              hipStream_t stream)
{
    const float* z = (const float*)d_in[0];
    float* out = (float*)d_out;

    const int B = in_sizes[0] / NZ;          // 2048
    const int nrows_total = B * NROW;        // 262144

    const int block = 256;
    const int grid = (nrows_total + block - 1) / block;
    chol_from_z_kernel<<<grid, block, 0, stream>>>(z, out, nrows_total);
}

// Round 2
// 56.452 us; speedup vs baseline: 4.9125x; 4.9125x over previous
//
#include <hip/hip_runtime.h>

#define NROW 128
#define NZ   8128      // 128*127/2
#define EPSF 1e-12f

// One WAVE (64 lanes) per (batch, row).
// Closed form: 1 - s_j = prod_{k<j} (1 - z_k^2)   (telescoping of the scan)
//   L[i,j] = z[i,j] * sqrt(max(P_j, EPS))  (j<i),  L[i,i] = sqrt(max(P_i, EPS)), 0 above.
// P_j = exclusive prefix product of masked factors f_k = (k<i ? 1-z_k^2 : 1).
// Lanes hold positions {lane, 64+lane}; multiplicative shuffle scan, 6 steps/half.
__global__ __launch_bounds__(256) void chol_from_z_kernel(
    const float* __restrict__ z, float* __restrict__ out, int nrows_total)
{
    const int gtid = blockIdx.x * blockDim.x + threadIdx.x;
    const int wid  = gtid >> 6;           // one wave per row
    const int lane = threadIdx.x & 63;
    if (wid >= nrows_total) return;

    const int b = wid >> 7;               // batch
    const int i = wid & 127;              // row within batch

    const float* __restrict__ zr = z + (size_t)b * NZ + (size_t)((i * (i - 1)) >> 1);

    const int p0 = lane;                  // position in row, first half
    const int p1 = 64 + lane;             // second half

    // Coalesced predicated loads (256B contiguous per instruction)
    const float z0 = (p0 < i) ? zr[p0] : 0.0f;
    const float z1 = (p1 < i) ? zr[p1] : 0.0f;

    // Masked factors
    float s0 = (p0 < i) ? fmaf(-z0, z0, 1.0f) : 1.0f;
    float s1 = (p1 < i) ? fmaf(-z1, z1, 1.0f) : 1.0f;

    // Inclusive multiplicative scan across 64 lanes, both halves
    #pragma unroll
    for (int off = 1; off < 64; off <<= 1) {
        const float t0 = __shfl_up(s0, off, 64);
        const float t1 = __shfl_up(s1, off, 64);
        if (lane >= off) { s0 *= t0; s1 *= t1; }
    }
    const float tot0 = __shfl(s0, 63, 64);   // product of entire first half

    // Exclusive prefixes
    float e0 = __shfl_up(s0, 1, 64);
    float e1 = __shfl_up(s1, 1, 64);
    if (lane == 0) { e0 = 1.0f; e1 = 1.0f; }
    e1 *= tot0;                              // chain across halves

    const float sq0 = sqrtf(fmaxf(e0, EPSF));
    const float sq1 = sqrtf(fmaxf(e1, EPSF));

    const float o0 = (p0 < i) ? z0 * sq0 : ((p0 == i) ? sq0 : 0.0f);
    const float o1 = (p1 < i) ? z1 * sq1 : ((p1 == i) ? sq1 : 0.0f);

    float* __restrict__ orow = out + (size_t)wid * NROW;
    orow[p0] = o0;                           // coalesced 256B store
    orow[p1] = o1;                           // coalesced 256B store
}

extern "C" void kernel_launch(void* const* d_in, const int* in_sizes, int n_in,
                              void* d_out, int out_size, void* d_ws, size_t ws_size,
                              hipStream_t stream)
{
    const float* z = (const float*)d_in[0];
    float* out = (float*)d_out;

    const int B = in_sizes[0] / NZ;              // 2048
    const int nrows_total = B * NROW;            // 262144 rows -> 262144 waves

    const int block = 256;                       // 4 waves/block
    const int grid = (nrows_total * 64 + block - 1) / block;  // 65536 blocks
    chol_from_z_kernel<<<grid, block, 0, stream>>>(z, out, nrows_total);
}